// Round 8
// baseline (191.576 us; speedup 1.0000x reference)
//
#include <hip/hip_runtime.h>

#define GXc 96
#define GYc 96
#define RFc 24
#define Bc 8
#define Nc (GXc * GYc)          // 9216
#define Hc (GXc - 1 + RFc)      // 119
#define IN_IMG (Hc * Hc)        // 14161
#define RF2 (RFc * RFc)         // 576
#define GAMMA 0.9f
#define INV_GAMMA (1.0f / 0.9f)

#define ROWS 2                  // output rows per wave
#define WPB 8                   // waves per block (512 threads)
#define RPB (ROWS * WPB)        // 16 rows per block
#define NBLOCKS (Nc / RPB)      // 576
#define KW 256                  // k-window (floats) = 64 lanes x float4
#define NWIN (Nc / KW)          // 36

__device__ __forceinline__ float dot4(float4 a, float4 b) {
    return a.x * b.x + a.y * b.y + a.z * b.z + a.w * b.w;
}

// Body J invariants on entry:
//   LDS slot (J&1) holds p-window J; q[(J+1)&1] holds p-window J+1 (regs);
//   wcur holds W-window J (regs).
// Body J actions:
//   1) issue p(J+2) -> q[J&1], W(J+1) -> wnext        (if in range)
//   2) FMA window J from LDS slot + wcur              (waits vmcnt(5): loads
//      issued one full body earlier; never drains the new prefetches)
//   3) ds_write q[(J+1)&1] -> slot ((J+1)&1)          (no extra vm wait:
//      p(J+1) is older than the vmcnt(5) horizon)
//   4) lgkmcnt(0); raw s_barrier                      (vmcnt NOT drained)
#define BODY(KBASE, SR, SW, WCUR, WNEXT, QLOAD, QWRITE, PREF_P, PREF_W)       \
  {                                                                           \
    if (PREF_P) {                                                             \
      const int k2 = (KBASE) + 2 * KW + koff;                                 \
      QLOAD = *(const float4*)(prev + wave * Nc + k2);                        \
    }                                                                         \
    if (PREF_W) {                                                             \
      const int k1 = (KBASE) + KW + koff;                                     \
      WNEXT[0] = *(const float4*)(r0e + k1);                                  \
      WNEXT[1] = *(const float4*)(r1e + k1);                                  \
      WNEXT[2] = *(const float4*)(r0i + k1);                                  \
      WNEXT[3] = *(const float4*)(r1i + k1);                                  \
    }                                                                         \
    __builtin_amdgcn_sched_barrier(0);                                        \
    {                                                                         \
      const float4 w0 = make_float4(WCUR[0].x - WCUR[2].x,                    \
                                    WCUR[0].y - WCUR[2].y,                    \
                                    WCUR[0].z - WCUR[2].z,                    \
                                    WCUR[0].w - WCUR[2].w);                   \
      const float4 w1 = make_float4(WCUR[1].x - WCUR[3].x,                    \
                                    WCUR[1].y - WCUR[3].y,                    \
                                    WCUR[1].z - WCUR[3].z,                    \
                                    WCUR[1].w - WCUR[3].w);                   \
      _Pragma("unroll")                                                       \
      for (int b = 0; b < Bc; ++b) {                                          \
        const float4 pb4 = *(const float4*)&pv[SR][b][koff];                  \
        acc[0][b] += dot4(w0, pb4);                                           \
        acc[1][b] += dot4(w1, pb4);                                           \
      }                                                                       \
    }                                                                         \
    __builtin_amdgcn_sched_barrier(0);                                        \
    if (PREF_P || PREF_W) {   /* last body writes nothing */                  \
      *(float4*)&pv[SW][wave][koff] = QWRITE;                                 \
    }                                                                         \
    asm volatile("s_waitcnt lgkmcnt(0)" ::: "memory");                        \
    __builtin_amdgcn_s_barrier();                                             \
    __builtin_amdgcn_sched_barrier(0);                                        \
  }

__global__ __launch_bounds__(512) void cortex_fused_kernel(
    const float* __restrict__ input,   // (B, 119, 119)
    const float* __restrict__ prev,    // (B, N)
    const float* __restrict__ aw,      // (N, 576)
    const float* __restrict__ We,      // (N, N)
    const float* __restrict__ Wi,      // (N, N)
    float* __restrict__ out)           // (B, N)
{
    __shared__ float pv[2][Bc][KW];    // 2-slot p-window buffer, 16 KB

    const int tid  = threadIdx.x;
    const int wave = tid >> 6;         // 0..7: also the batch this wave stages
    const int lane = tid & 63;
    const int rowbase = blockIdx.x * RPB + wave * ROWS;
    const int koff = lane << 2;

    float acc[ROWS][Bc];
#pragma unroll
    for (int r = 0; r < ROWS; ++r)
#pragma unroll
        for (int b = 0; b < Bc; ++b) acc[r][b] = 0.f;

    // ---------------- afferent (local RF conv), all-lane k layout ----------
#pragma unroll
    for (int r = 0; r < ROWS; ++r) {
        const int n  = rowbase + r;
        const int gi = n / GYc;
        const int gj = n - gi * GYc;
        const float* awn = aw + (size_t)n * RF2;
        const int base = gi * Hc + gj;
#pragma unroll
        for (int t = 0; t < RF2 / 64; ++t) {   // 9 iters
            const int hw = t * 64 + lane;
            const int h  = hw / RFc;
            const int w  = hw - h * RFc;
            const float av = awn[hw] * INV_GAMMA;
            const int off  = base + h * Hc + w;
#pragma unroll
            for (int b = 0; b < Bc; ++b)
                acc[r][b] += input[b * IN_IMG + off] * av;
        }
    }

    // ---------------- lateral: prev @ (We - Wi)^T --------------------------
    const float* r0e = We + (size_t)(rowbase + 0) * Nc;
    const float* r1e = We + (size_t)(rowbase + 1) * Nc;
    const float* r0i = Wi + (size_t)(rowbase + 0) * Nc;
    const float* r1i = Wi + (size_t)(rowbase + 1) * Nc;

    float4 wA[4], wB[4], q0, q1;

    // prologue: p(0)->q0, p(1)->q1, W(0)->wA; write slot0<-p(0); barrier.
    {
        q0 = *(const float4*)(prev + wave * Nc + koff);
        q1 = *(const float4*)(prev + wave * Nc + KW + koff);
        wA[0] = *(const float4*)(r0e + koff);
        wA[1] = *(const float4*)(r1e + koff);
        wA[2] = *(const float4*)(r0i + koff);
        wA[3] = *(const float4*)(r1i + koff);
        *(float4*)&pv[0][wave][koff] = q0;
        asm volatile("s_waitcnt lgkmcnt(0)" ::: "memory");
        __builtin_amdgcn_s_barrier();
        __builtin_amdgcn_sched_barrier(0);
    }

    // steady state: bodies 0..33 (17 x 2)
    for (int t = 0; t < 17; ++t) {
        const int kb0 = (2 * t) * KW;
        BODY(kb0,      0, 1, wA, wB, q0, q1, true, true);   // even body
        BODY(kb0 + KW, 1, 0, wB, wA, q1, q0, true, true);   // odd body
    }
    // tail: body 34 (load W(35) only; write p(35)); body 35 (consume only)
    BODY(34 * KW, 0, 1, wA, wB, q0, q1, false, true);
    BODY(35 * KW, 1, 0, wB, wA, q1, q0, false, false);

    // ---------------- butterfly reduce + static-index epilogue -------------
#pragma unroll
    for (int r = 0; r < ROWS; ++r)
#pragma unroll
        for (int b = 0; b < Bc; ++b) {
            float v = acc[r][b];
            v += __shfl_xor(v, 1);
            v += __shfl_xor(v, 2);
            v += __shfl_xor(v, 4);
            v += __shfl_xor(v, 8);
            v += __shfl_xor(v, 16);
            v += __shfl_xor(v, 32);
            if (lane == b * ROWS + r) {          // compile-time (r,b) per instance
                const float tot = GAMMA * v;
                out[b * Nc + rowbase + r] = tot > 0.f ? tot : 0.f;
            }
        }
}

extern "C" void kernel_launch(void* const* d_in, const int* in_sizes, int n_in,
                              void* d_out, int out_size, void* d_ws, size_t ws_size,
                              hipStream_t stream) {
    const float* input = (const float*)d_in[0];
    const float* prev  = (const float*)d_in[1];
    const float* aw    = (const float*)d_in[2];
    const float* We    = (const float*)d_in[3];
    const float* Wi    = (const float*)d_in[4];
    // d_in[5], d_in[6] are rf_x / rf_y == arange(96): identity, folded into indexing.
    float* out = (float*)d_out;

    cortex_fused_kernel<<<NBLOCKS, 512, 0, stream>>>(input, prev, aw, We, Wi, out);
}

// Round 9
// 176.570 us; speedup vs baseline: 1.0850x; 1.0850x over previous
//
#include <hip/hip_runtime.h>

#define GXc 96
#define GYc 96
#define RFc 24
#define Bc 8
#define Nc (GXc * GYc)          // 9216
#define Hc (GXc - 1 + RFc)      // 119
#define IN_IMG (Hc * Hc)        // 14161
#define RF2 (RFc * RFc)         // 576
#define GAMMA 0.9f

// ---------------- Kernel A: afferent with LDS input tiling -----------------
// Block = (gi, 16-wide gj chunk). Stage input rows gi..gi+23, cols
// gj0..gj0+38 for all 8 batches into LDS once; 4 waves x 4 n's consume it.
#define A_GJW 16                              // gj chunk per block
#define A_COLS (A_GJW - 1 + RFc)              // 39
#define A_PAD 40
#define A_NBLK (GXc * (GYc / A_GJW))          // 96 * 6 = 576

__global__ __launch_bounds__(256) void afferent_kernel(
    const float* __restrict__ input,   // (B, 119, 119)
    const float* __restrict__ aw,      // (N, 576)
    float* __restrict__ aff)           // (B, N) scratch
{
    __shared__ float li[Bc][RFc][A_PAD];      // 30.7 KB

    const int tid  = threadIdx.x;
    const int wave = tid >> 6;
    const int lane = tid & 63;
    const int gi   = blockIdx.x / (GYc / A_GJW);
    const int gj0  = (blockIdx.x % (GYc / A_GJW)) * A_GJW;

    // stage the shared input patch
    for (int i = tid; i < Bc * RFc * A_COLS; i += 256) {
        const int b = i / (RFc * A_COLS);
        const int rem = i - b * (RFc * A_COLS);
        const int h = rem / A_COLS;
        const int c = rem - h * A_COLS;
        li[b][h][c] = input[b * IN_IMG + (gi + h) * Hc + gj0 + c];
    }
    __syncthreads();

#pragma unroll
    for (int q = 0; q < 4; ++q) {
        const int cc = wave * 4 + q;          // 0..15
        const int n  = gi * GYc + gj0 + cc;
        const float* awn = aw + (size_t)n * RF2;
        float acc[Bc];
#pragma unroll
        for (int b = 0; b < Bc; ++b) acc[b] = 0.f;
#pragma unroll
        for (int t = 0; t < RF2 / 64; ++t) {  // 9 iters
            const int hw = t * 64 + lane;
            const int h  = hw / RFc;
            const int w  = hw - h * RFc;
            const float av = awn[hw];
#pragma unroll
            for (int b = 0; b < Bc; ++b)
                acc[b] += li[b][h][cc + w] * av;
        }
#pragma unroll
        for (int b = 0; b < Bc; ++b) {
            float v = acc[b];
            v += __shfl_xor(v, 1);
            v += __shfl_xor(v, 2);
            v += __shfl_xor(v, 4);
            v += __shfl_xor(v, 8);
            v += __shfl_xor(v, 16);
            v += __shfl_xor(v, 32);
            if (lane == b) aff[b * Nc + n] = v;
        }
    }
}

// ---------------- Kernel B: lateral stream + epilogue ----------------------
#define ROWS 3                  // output rows per wave
#define WPB 4                   // waves per block
#define RPB (ROWS * WPB)        // 12 rows per block
#define NBLOCKS (Nc / RPB)      // 768 = exactly 3 blocks/CU
#define KW 256                  // k-window (floats)
#define NWIN (Nc / KW)          // 36

__device__ __forceinline__ float dot4(float4 a, float4 b) {
    return a.x * b.x + a.y * b.y + a.z * b.z + a.w * b.w;
}

// Invariants entering body J: LDS slot (J&1) holds p(J); QW regs hold p(J+1);
// WCUR holds W(J). Never drains vmcnt below the prefetch depth.
#define BODY(KBASE, SR, SW, WCUR, WNEXT, QL0, QL1, QW0, QW1, PREF_P, PREF_W)  \
  {                                                                           \
    if (PREF_P) {                                                             \
      const int k2 = (KBASE) + 2 * KW + koff;                                 \
      QL0 = *(const float4*)(prev + sb0 * Nc + k2);                           \
      QL1 = *(const float4*)(prev + sb1 * Nc + k2);                           \
    }                                                                         \
    if (PREF_W) {                                                             \
      const int k1 = (KBASE) + KW + koff;                                     \
      WNEXT[0] = *(const float4*)(rE0 + k1);                                  \
      WNEXT[1] = *(const float4*)(rE1 + k1);                                  \
      WNEXT[2] = *(const float4*)(rE2 + k1);                                  \
      WNEXT[3] = *(const float4*)(rI0 + k1);                                  \
      WNEXT[4] = *(const float4*)(rI1 + k1);                                  \
      WNEXT[5] = *(const float4*)(rI2 + k1);                                  \
    }                                                                         \
    __builtin_amdgcn_sched_barrier(0);                                        \
    {                                                                         \
      const float4 w0 = make_float4(WCUR[0].x - WCUR[3].x,                    \
                                    WCUR[0].y - WCUR[3].y,                    \
                                    WCUR[0].z - WCUR[3].z,                    \
                                    WCUR[0].w - WCUR[3].w);                   \
      const float4 w1 = make_float4(WCUR[1].x - WCUR[4].x,                    \
                                    WCUR[1].y - WCUR[4].y,                    \
                                    WCUR[1].z - WCUR[4].z,                    \
                                    WCUR[1].w - WCUR[4].w);                   \
      const float4 w2 = make_float4(WCUR[2].x - WCUR[5].x,                    \
                                    WCUR[2].y - WCUR[5].y,                    \
                                    WCUR[2].z - WCUR[5].z,                    \
                                    WCUR[2].w - WCUR[5].w);                   \
      _Pragma("unroll")                                                       \
      for (int b = 0; b < Bc; ++b) {                                          \
        const float4 pb4 = *(const float4*)&pv[SR][b][koff];                  \
        acc[0][b] += dot4(w0, pb4);                                           \
        acc[1][b] += dot4(w1, pb4);                                           \
        acc[2][b] += dot4(w2, pb4);                                           \
      }                                                                       \
    }                                                                         \
    __builtin_amdgcn_sched_barrier(0);                                        \
    if ((PREF_P) || (PREF_W)) {                                               \
      *(float4*)&pv[SW][sb0][koff] = QW0;                                     \
      *(float4*)&pv[SW][sb1][koff] = QW1;                                     \
    }                                                                         \
    asm volatile("s_waitcnt lgkmcnt(0)" ::: "memory");                        \
    __builtin_amdgcn_s_barrier();                                             \
    __builtin_amdgcn_sched_barrier(0);                                        \
  }

__global__ __launch_bounds__(256) void lateral_kernel(
    const float* __restrict__ prev,    // (B, N)
    const float* __restrict__ We,      // (N, N)
    const float* __restrict__ Wi,      // (N, N)
    const float* __restrict__ aff,     // (B, N) from kernel A
    float* __restrict__ out)           // (B, N)
{
    __shared__ float pv[2][Bc][KW];    // 2-slot p-window buffer, 16 KB

    const int tid  = threadIdx.x;
    const int wave = tid >> 6;
    const int lane = tid & 63;
    const int rowbase = blockIdx.x * RPB + wave * ROWS;
    const int koff = lane << 2;
    const int sb0 = wave * 2;          // this wave stages these 2 batches
    const int sb1 = wave * 2 + 1;

    const float* rE0 = We + (size_t)(rowbase + 0) * Nc;
    const float* rE1 = We + (size_t)(rowbase + 1) * Nc;
    const float* rE2 = We + (size_t)(rowbase + 2) * Nc;
    const float* rI0 = Wi + (size_t)(rowbase + 0) * Nc;
    const float* rI1 = Wi + (size_t)(rowbase + 1) * Nc;
    const float* rI2 = Wi + (size_t)(rowbase + 2) * Nc;

    float acc[ROWS][Bc];
#pragma unroll
    for (int r = 0; r < ROWS; ++r)
#pragma unroll
        for (int b = 0; b < Bc; ++b) acc[r][b] = 0.f;

    float4 wA[6], wB[6], qE0, qE1, qO0, qO1;

    // prologue: p(0)->qE, p(1)->qO, W(0)->wA; slot0 <- p(0); barrier.
    {
        qE0 = *(const float4*)(prev + sb0 * Nc + koff);
        qE1 = *(const float4*)(prev + sb1 * Nc + koff);
        qO0 = *(const float4*)(prev + sb0 * Nc + KW + koff);
        qO1 = *(const float4*)(prev + sb1 * Nc + KW + koff);
        wA[0] = *(const float4*)(rE0 + koff);
        wA[1] = *(const float4*)(rE1 + koff);
        wA[2] = *(const float4*)(rE2 + koff);
        wA[3] = *(const float4*)(rI0 + koff);
        wA[4] = *(const float4*)(rI1 + koff);
        wA[5] = *(const float4*)(rI2 + koff);
        *(float4*)&pv[0][sb0][koff] = qE0;
        *(float4*)&pv[0][sb1][koff] = qE1;
        asm volatile("s_waitcnt lgkmcnt(0)" ::: "memory");
        __builtin_amdgcn_s_barrier();
        __builtin_amdgcn_sched_barrier(0);
    }

    // bodies 0..33
    for (int t = 0; t < 17; ++t) {
        const int kb = (2 * t) * KW;
        BODY(kb,      0, 1, wA, wB, qE0, qE1, qO0, qO1, true, true);
        BODY(kb + KW, 1, 0, wB, wA, qO0, qO1, qE0, qE1, true, true);
    }
    // body 34: no p(36); load W(35); write p(35)(=qO). body 35: consume only.
    BODY(34 * KW, 0, 1, wA, wB, qE0, qE1, qO0, qO1, false, true);
    BODY(35 * KW, 1, 0, wB, wA, qO0, qO1, qE0, qE1, false, false);

    // ---------------- butterfly reduce + epilogue --------------------------
#pragma unroll
    for (int r = 0; r < ROWS; ++r)
#pragma unroll
        for (int b = 0; b < Bc; ++b) {
            float v = acc[r][b];
            v += __shfl_xor(v, 1);
            v += __shfl_xor(v, 2);
            v += __shfl_xor(v, 4);
            v += __shfl_xor(v, 8);
            v += __shfl_xor(v, 16);
            v += __shfl_xor(v, 32);
            if (lane == b * ROWS + r) {        // compile-time (r,b) per instance
                const int n = rowbase + r;
                const float tot = aff[b * Nc + n] + GAMMA * v;
                out[b * Nc + n] = tot > 0.f ? tot : 0.f;
            }
        }
}

extern "C" void kernel_launch(void* const* d_in, const int* in_sizes, int n_in,
                              void* d_out, int out_size, void* d_ws, size_t ws_size,
                              hipStream_t stream) {
    const float* input = (const float*)d_in[0];
    const float* prev  = (const float*)d_in[1];
    const float* aw    = (const float*)d_in[2];
    const float* We    = (const float*)d_in[3];
    const float* Wi    = (const float*)d_in[4];
    float* out = (float*)d_out;
    float* aff = (float*)d_ws;         // 8*9216*4 = 295 KB scratch

    afferent_kernel<<<A_NBLK, 256, 0, stream>>>(input, aw, aff);
    lateral_kernel<<<NBLOCKS, 256, 0, stream>>>(prev, We, Wi, aff, out);
}